// Round 2
// baseline (691.277 us; speedup 1.0000x reference)
//
#include <hip/hip_runtime.h>

#define NP 128
#define NPE 127
#define FDIM 32
#define RSTRIDE 36

// LDS float offsets for staged fp32 weights
#define O_W1  0      // e_w1 66x32
#define O_B1  2112
#define O_W2  2144   // e_w2 32x32
#define O_B2  3168
#define O_CW1 3200   // c_w1 32x32
#define O_CB1 4224
#define O_CW2 4256   // c_w2 32
#define O_AW  4288   // a_w 32
#define O_AB  4320   // a_b 1 (padded to 4)
#define O_NW1 4324   // n_w1 64x32
#define O_NB1 6372
#define O_NW2 6404   // n_w2 32x32
#define O_NB2 7428
#define W_TOTAL 7460
#define SMEM_FLOATS (W_TOTAL + 128 * RSTRIDE)

__device__ __forceinline__ float fast_rcp(float x) { return __builtin_amdgcn_rcpf(x); }
__device__ __forceinline__ float sigmoidf_(float x) { return fast_rcp(1.0f + __expf(-x)); }
__device__ __forceinline__ float siluf(float x) { return x * sigmoidf_(x); }
__device__ __forceinline__ float tanhf_fast(float x) {
    // tanh(x) = 1 - 2/(exp(2x)+1); saturates correctly at +/-inf
    return 1.0f - 2.0f * fast_rcp(1.0f + __expf(2.0f * x));
}

// One dense layer: out32 = act(in[K] @ W[K][32] + b[32]).
// Weights broadcast from LDS (uniform addr); activations in registers
// (k-loop fully unrolled); rolled g-loop round-trips through this thread's
// private LDS row to avoid dynamic register indexing.
template<int K, bool SILU>
__device__ __forceinline__ void mlp_layer(const float* sw, int woff, int boff,
                                          const float (&in)[K], float* row,
                                          float (&out)[32])
{
    for (int g = 0; g < 4; ++g) {
        float4 a0 = *(const float4*)&sw[boff + g * 8];
        float4 a1 = *(const float4*)&sw[boff + g * 8 + 4];
        #pragma unroll
        for (int kk = 0; kk < K; ++kk) {
            const float a = in[kk];
            const float4 w0 = *(const float4*)&sw[woff + kk * 32 + g * 8];
            const float4 w1 = *(const float4*)&sw[woff + kk * 32 + g * 8 + 4];
            a0.x = fmaf(a, w0.x, a0.x); a0.y = fmaf(a, w0.y, a0.y);
            a0.z = fmaf(a, w0.z, a0.z); a0.w = fmaf(a, w0.w, a0.w);
            a1.x = fmaf(a, w1.x, a1.x); a1.y = fmaf(a, w1.y, a1.y);
            a1.z = fmaf(a, w1.z, a1.z); a1.w = fmaf(a, w1.w, a1.w);
        }
        if (SILU) {
            a0.x = siluf(a0.x); a0.y = siluf(a0.y); a0.z = siluf(a0.z); a0.w = siluf(a0.w);
            a1.x = siluf(a1.x); a1.y = siluf(a1.y); a1.z = siluf(a1.z); a1.w = siluf(a1.w);
        }
        *(float4*)&row[g * 8]     = a0;
        *(float4*)&row[g * 8 + 4] = a1;
    }
    #pragma unroll
    for (int g = 0; g < 8; ++g) {
        const float4 v = *(const float4*)&row[g * 4];
        out[g * 4 + 0] = v.x; out[g * 4 + 1] = v.y;
        out[g * 4 + 2] = v.z; out[g * 4 + 3] = v.w;
    }
}

__global__ __launch_bounds__(128)
void eq_gnn_kernel(const float* __restrict__ X, const float* __restrict__ Hin,
                   const float* __restrict__ DS,
                   const float* EW1, const float* EB1, const float* EW2, const float* EB2,
                   const float* NW1, const float* NB1, const float* NW2, const float* NB2,
                   const float* CW1, const float* CB1, const float* CW2,
                   const float* AW,  const float* AB,
                   float* __restrict__ OUT)
{
    __shared__ float smem[SMEM_FLOATS];
    const int t = threadIdx.x;
    const int b = blockIdx.x >> 7;
    const int i = blockIdx.x & 127;

    // ---- stage all weights to LDS ----
    {
        const float* srcs[13] = {EW1, EB1, EW2, EB2, CW1, CB1, CW2, AW, AB, NW1, NB1, NW2, NB2};
        const int    offs[13] = {O_W1, O_B1, O_W2, O_B2, O_CW1, O_CB1, O_CW2, O_AW, O_AB, O_NW1, O_NB1, O_NW2, O_NB2};
        const int    cnts[13] = {2112, 32, 1024, 32, 1024, 32, 32, 32, 1, 2048, 32, 1024, 32};
        #pragma unroll
        for (int a = 0; a < 13; ++a) {
            for (int idx = t; idx < cnts[a]; idx += 128)
                smem[offs[a] + idx] = srcs[a][idx];
        }
    }
    __syncthreads();

    float* sred = &smem[W_TOTAL];
    float* row  = &sred[t * RSTRIDE];

    // ---- edge geometry ----
    const int jslot = (t < NPE) ? t : 0;
    const int j = jslot + ((jslot >= i) ? 1 : 0);

    const float xi0 = X[b * 384 + i * 3 + 0];
    const float xi1 = X[b * 384 + i * 3 + 1];
    const float xi2 = X[b * 384 + i * 3 + 2];
    const float xj0 = X[b * 384 + j * 3 + 0];
    const float xj1 = X[b * 384 + j * 3 + 1];
    const float xj2 = X[b * 384 + j * 3 + 2];
    const float r0 = xi0 - xj0, r1 = xi1 - xj1, r2 = xi2 - xj2;
    const float rr = r0 * r0 + r1 * r1 + r2 * r2 + 1e-6f;
    const float d  = sqrtf(rr);
    const float d2 = d * d;
    const float dsv = DS[b * 16256 + i * 127 + jslot];
    const float ds2 = dsv * dsv;

    // ---- e_in = [h_i, h_j, d^2, ds^2] ----
    float ein[66];
    const float* hi_p = &Hin[(b * NP + i) * FDIM];
    const float* hj_p = &Hin[(b * NP + j) * FDIM];
    #pragma unroll
    for (int g = 0; g < 8; ++g) {
        const float4 vi = *(const float4*)&hi_p[g * 4];
        const float4 vj = *(const float4*)&hj_p[g * 4];
        ein[g*4+0] = vi.x; ein[g*4+1] = vi.y; ein[g*4+2] = vi.z; ein[g*4+3] = vi.w;
        ein[32+g*4+0] = vj.x; ein[32+g*4+1] = vj.y; ein[32+g*4+2] = vj.z; ein[32+g*4+3] = vj.w;
    }
    ein[64] = d2; ein[65] = ds2;

    // ---- edge MLP ----
    float t1[32], m[32], c1[32];
    mlp_layer<66, true>(smem, O_W1, O_B1, ein, row, t1);
    mlp_layer<32, true>(smem, O_W2, O_B2, t1, row, m);

    // attention gate
    float aacc = smem[O_AB];
    #pragma unroll
    for (int k = 0; k < 32; ++k) aacc = fmaf(m[k], smem[O_AW + k], aacc);
    const float att = sigmoidf_(aacc);
    #pragma unroll
    for (int k = 0; k < 32; ++k) m[k] *= att;

    // coord head
    mlp_layer<32, true>(smem, O_CW1, O_CB1, m, row, c1);
    float tr = 0.f;
    #pragma unroll
    for (int k = 0; k < 32; ++k) tr = fmaf(c1[k], smem[O_CW2 + k], tr);
    const float trans = tanhf_fast(tr);
    const float coef  = trans * fast_rcp(d + 1.0f);

    // ---- stash per-edge m (gated) + coord contribution for reduction ----
    if (t < NPE) {
        #pragma unroll
        for (int g = 0; g < 8; ++g)
            *(float4*)&row[g * 4] = make_float4(m[g*4], m[g*4+1], m[g*4+2], m[g*4+3]);
        *(float4*)&row[32] = make_float4(r0 * coef, r1 * coef, r2 * coef, 0.f);
    } else {
        #pragma unroll
        for (int g = 0; g < 9; ++g)
            *(float4*)&row[g * 4] = make_float4(0.f, 0.f, 0.f, 0.f);
    }
    __syncthreads();

    // ---- tree reduction over 128 rows x 36 cols ----
    for (int s = 64; s > 0; s >>= 1) {
        if (t < s) {
            float* pa = &sred[t * RSTRIDE];
            const float* pb = &sred[(t + s) * RSTRIDE];
            #pragma unroll
            for (int c = 0; c < 36; c += 4) {
                float4 va = *(float4*)&pa[c];
                const float4 vb = *(const float4*)&pb[c];
                va.x += vb.x; va.y += vb.y; va.z += vb.z; va.w += vb.w;
                *(float4*)&pa[c] = va;
            }
        }
        __syncthreads();
    }
    // row 0: cols 0..31 = m_i, cols 32..34 = sum of r/(d+1)*trans

    // ---- x output ----
    if (t < 3) {
        const float xiv = (t == 0) ? xi0 : ((t == 1) ? xi1 : xi2);
        OUT[b * 384 + i * 3 + t] = xiv + sred[32 + t] * 5.0f;
    }

    // ---- node MLP: h_upd = silu([h, m_i] @ n_w1 + n_b1) @ n_w2 + n_b2 ----
    if (t < 32) {
        float acc = smem[O_NB1 + t];
        const float* hp = &Hin[(b * NP + i) * FDIM];
        #pragma unroll
        for (int kk = 0; kk < 64; ++kk) {
            const float a = (kk < 32) ? hp[kk] : sred[kk - 32];
            acc = fmaf(a, smem[O_NW1 + kk * 32 + t], acc);
        }
        sred[40 + t] = siluf(acc);
    }
    __syncthreads();
    if (t < 32) {
        float acc = smem[O_NB2 + t];
        #pragma unroll
        for (int kk = 0; kk < 32; ++kk)
            acc = fmaf(sred[40 + kk], smem[O_NW2 + kk * 32 + t], acc);
        const float ho = Hin[(b * NP + i) * FDIM + t] + acc;
        OUT[49152 + (b * NP + i) * FDIM + t] = ho;
    }
}

extern "C" void kernel_launch(void* const* d_in, const int* in_sizes, int n_in,
                              void* d_out, int out_size, void* d_ws, size_t ws_size,
                              hipStream_t stream) {
    (void)in_sizes; (void)n_in; (void)out_size; (void)d_ws; (void)ws_size;
    eq_gnn_kernel<<<dim3(128 * 128), dim3(128), 0, stream>>>(
        (const float*)d_in[0],  (const float*)d_in[1],  (const float*)d_in[2],
        (const float*)d_in[3],  (const float*)d_in[4],  (const float*)d_in[5],  (const float*)d_in[6],
        (const float*)d_in[7],  (const float*)d_in[8],  (const float*)d_in[9],  (const float*)d_in[10],
        (const float*)d_in[11], (const float*)d_in[12], (const float*)d_in[13],
        (const float*)d_in[14], (const float*)d_in[15],
        (float*)d_out);
}